// Round 10
// baseline (5043.629 us; speedup 1.0000x reference)
//
#include <hip/hip_runtime.h>
#include <stdint.h>

// FPS: B=16, C=3, N=131072, M=2048. 256 blocks (16/batch) x 1024 thr, 1/CU.
//
// R10 = R6 protocol + MEASURED XCD co-location + XCD-L2 fast barrier.
//  - R9 evidence: agent-scope atomics ALSO write through to HBM (WRITE_SIZE
//    bit-identical to R6) => cross-XCD RTT ~1.1us is scope-fixed. The only
//    sub-us medium is the XCD-local L2. R8 showed bid&7 co-location is
//    FALSE, so: read the REAL XCD via s_getreg(HW_REG_XCC_ID) [m09] and
//    claim roles per-XCD (batch = xcc*2 + (r>>4), sub = r&15). Surplus
//    blocks steal unclaimed roles (256 roles = 256 blocks => terminates;
//    stolen role = that batch de-colocated = falls back, still correct).
//  - Fast path: WORKGROUP-scope atomicExch/fetch_add(0) on global slots —
//    atomics execute at the local XCD L2 (no sc1), 8B single-op (no tear),
//    full-width tag. Agent-scope line (R6) polled every 4th round as the
//    always-correct fallback. Mixed batches cannot false-positive the fast
//    ballot: all-16-tags==t => values are the unique t-tagged publishes.
//  - R7 lesson kept: sleeping waves (syncthreads), single converged poller.
// Numerics (bit-matches XLA-CPU ref, verified R2..R9):
//   d = fma(dz,dz, fma(dy,dy, dx*dx)); key=[distBits:32][invIdx:17], tag@49.

#define NBATCH    16
#define NPTS      131072
#define SUBBLOCKS 16
#define NTHREADS  1024
#define CHUNK     8192
#define HALF      4096

typedef unsigned long long u64;
typedef unsigned int u32;

__device__ __forceinline__ u64 umax64(u64 a, u64 b) { return a > b ? a : b; }

__global__ __launch_bounds__(NTHREADS, 4)
void fps_kernel(const float* __restrict__ points,
                float* __restrict__ out,
                u64* __restrict__ dslots,   // agent-scope slots (R6 path)
                u64* __restrict__ lslots,   // XCD-L2 fast-path slots
                u32* __restrict__ cnts,     // per-XCD role counters [8]
                int M)
{
  __shared__ u64 wkeys[NTHREADS / 64];
  __shared__ u64 winner_s;
  __shared__ int role_s;

  const int tid  = threadIdx.x;
  const int wave = tid >> 6;
  const int lane = tid & 63;

  // ---- role claim: co-locate each batch's 16 blocks on ONE real XCD ----
  if (tid == 0) {
    u32 xcc;
    asm volatile("s_getreg_b32 %0, hwreg(HW_REG_XCC_ID)" : "=s"(xcc));
    xcc &= 7u;
    int role;
    u32 r = atomicAdd(&cnts[xcc], 1u);
    if (r < 32u) {
      role = (int)(xcc * 32u + r);
    } else {
      for (;;) {                       // steal an unclaimed role elsewhere
        bool got = false;
        for (int x = 0; x < 8; ++x) {
          u32 c = __hip_atomic_load(&cnts[x], __ATOMIC_RELAXED,
                                    __HIP_MEMORY_SCOPE_AGENT);
          if (c < 32u) {
            u32 rr = atomicAdd(&cnts[x], 1u);
            if (rr < 32u) { role = x * 32 + (int)rr; got = true; break; }
          }
        }
        if (got) break;
      }
    }
    role_s = role;
  }
  __syncthreads();
  const int role  = role_s;
  const int rr    = role & 31;
  const int batch = (role >> 5) * 2 + (rr >> 4);
  const int sub   = rr & 15;

  const float* __restrict__ px = points + (size_t)batch * 3 * NPTS;
  const float* __restrict__ py = px + NPTS;
  const float* __restrict__ pz = px + 2 * NPTS;
  float* outb = out + (size_t)batch * 3 * M;
  u64* dbase = dslots + (size_t)batch * 2 * SUBBLOCKS;
  u64* lbase = lslots + (size_t)batch * 2 * SUBBLOCKS;

  const int cbase = sub * CHUNK;
  const int g0 = cbase + (tid << 2);
  const int g1 = g0 + HALF;

  // Load this thread's 8 points (2 x float4 per plane, coalesced).
  float4 A0 = *(const float4*)(px + g0);
  float4 B0 = *(const float4*)(py + g0);
  float4 C0 = *(const float4*)(pz + g0);
  float4 A1 = *(const float4*)(px + g1);
  float4 B1 = *(const float4*)(py + g1);
  float4 C1 = *(const float4*)(pz + g1);
  float x0=A0.x, x1=A0.y, x2=A0.z, x3=A0.w, x4=A1.x, x5=A1.y, x6=A1.z, x7=A1.w;
  float y0=B0.x, y1=B0.y, y2=B0.z, y3=B0.w, y4=B1.x, y5=B1.y, y6=B1.z, y7=B1.w;
  float z0=C0.x, z1=C0.y, z2=C0.z, z3=C0.w, z4=C1.x, z5=C1.y, z6=C1.z, z7=C1.w;
  // Pin coords (opaque to optimizer; prevents in-loop rematerialization).
  asm volatile("" :
    "+v"(x0),"+v"(x1),"+v"(x2),"+v"(x3),"+v"(x4),"+v"(x5),"+v"(x6),"+v"(x7),
    "+v"(y0),"+v"(y1),"+v"(y2),"+v"(y3),"+v"(y4),"+v"(y5),"+v"(y6),"+v"(y7),
    "+v"(z0),"+v"(z1),"+v"(z2),"+v"(z3),"+v"(z4),"+v"(z5),"+v"(z6),"+v"(z7));

  float d0, d1, d2, d3, d4, d5, d6, d7;
  d0 = d1 = d2 = d3 = d4 = d5 = d6 = d7 = __builtin_inff();

  // Selection 0 is index 0 by convention.
  if (sub == 0 && tid == 0) {
    outb[0]     = px[0];
    outb[M]     = py[0];
    outb[2 * M] = pz[0];
  }

  int sel = 0;
  for (int t = 1; t < M; ++t) {
    // Centroid = previously selected point (uniform broadcast loads, L2-hot).
    float cx = px[sel], cy = py[sel], cz = pz[sel];

    float best = -1.0f;
    int bidx = 0;
    // d = fma(dz,dz, fma(dy,dy, dx*dx)); ascending index => first-max kept.
#define STEP(XX, YY, ZZ, DREG, IDX) { \
    float dx = __fsub_rn((XX), cx); \
    float dy = __fsub_rn((YY), cy); \
    float dz = __fsub_rn((ZZ), cz); \
    float dd = __builtin_fmaf(dz, dz, __builtin_fmaf(dy, dy, __fmul_rn(dx, dx))); \
    DREG = DREG < dd ? DREG : dd; \
    if (DREG > best) { best = DREG; bidx = (IDX); } }
    STEP(x0, y0, z0, d0, g0 + 0)
    STEP(x1, y1, z1, d1, g0 + 1)
    STEP(x2, y2, z2, d2, g0 + 2)
    STEP(x3, y3, z3, d3, g0 + 3)
    STEP(x4, y4, z4, d4, g1 + 0)
    STEP(x5, y5, z5, d5, g1 + 1)
    STEP(x6, y6, z6, d6, g1 + 2)
    STEP(x7, y7, z7, d7, g1 + 3)

    // Pack [distBits:32 @17][invIdx:17 @0]; non-negative f32 bits are
    // order-preserving; invIdx breaks ties toward the SMALLEST index.
    u64 key = ((u64)__float_as_uint(best) << 17) | (u64)((NPTS - 1) - bidx);

    // Per-wave butterfly (parallel across all 16 waves).
#pragma unroll
    for (int m = 32; m >= 1; m >>= 1) {
      u64 o = __shfl_xor(key, m, 64);
      key = umax64(key, o);
    }
    if (lane == 0) wkeys[wave] = key;
    __syncthreads();

    if (wave == 0) {
      // Block reduce: lanes mirror wkeys[lane&15], 4-step butterfly.
      u64 k = wkeys[lane & 15];
#pragma unroll
      for (int m = 8; m >= 1; m >>= 1) {
        u64 o = __shfl_xor(k, m, 64);
        k = umax64(k, o);
      }
      u64* dpar = dbase + (size_t)(t & 1) * SUBBLOCKS;
      u64* lpar = lbase + (size_t)(t & 1) * SUBBLOCKS;
      const u64 tagged = ((u64)t << 49) | k;

      if (lane == 0) {
        // Fast publish: workgroup-scope atomic RMW -> executes at the
        // LOCAL XCD L2 (no sc1), visible to same-XCD pollers in ~200cyc.
        (void)__hip_atomic_exchange(lpar + sub, tagged,
                                    __ATOMIC_RELAXED,
                                    __HIP_MEMORY_SCOPE_WORKGROUP);
        // Slow publish: agent-scope (memory-side), always correct.
        __hip_atomic_store(dpar + sub, tagged,
                           __ATOMIC_RELAXED, __HIP_MEMORY_SCOPE_AGENT);
      }

      // Single converged poller: tight L2-atomic rounds on the fast line,
      // agent-scope check every 4th round (covers de-colocated batches).
      const bool poller = (lane < SUBBLOCKS);
      u64 v = 0;
      for (int round = 1;; ++round) {
        if (poller) {
          v = __hip_atomic_fetch_add((u64*)(lpar + lane), 0ull,
                                     __ATOMIC_RELAXED,
                                     __HIP_MEMORY_SCOPE_WORKGROUP);
        }
        bool ok = !poller | ((unsigned)(v >> 49) == (unsigned)t);
        if (__ballot(ok) == ~0ull) break;
        if ((round & 3) == 0) {
          u64 w = 0;
          if (poller) {
            w = __hip_atomic_load(dpar + lane, __ATOMIC_RELAXED,
                                  __HIP_MEMORY_SCOPE_AGENT);
          }
          bool ok2 = !poller | ((unsigned)(w >> 49) == (unsigned)t);
          if (__ballot(ok2) == ~0ull) { v = w; break; }
        }
      }
      // Reduce the 16 slot values (non-pollers hold 0 < any tagged value).
#pragma unroll
      for (int m = 8; m >= 1; m >>= 1) {
        u64 o = __shfl_xor(v, m, 64);
        v = umax64(v, o);
      }
      if (lane == 0) winner_s = v;
    }
    __syncthreads();

    sel = (NPTS - 1) - (int)(winner_s & 0x1FFFF);

    if (sub == 0 && tid == 0) {
      outb[t]         = px[sel];
      outb[M + t]     = py[sel];
      outb[2 * M + t] = pz[sel];
    }
  }
}

extern "C" void kernel_launch(void* const* d_in, const int* in_sizes, int n_in,
                              void* d_out, int out_size, void* d_ws, size_t ws_size,
                              hipStream_t stream) {
  (void)in_sizes; (void)n_in; (void)ws_size;
  const float* points = (const float*)d_in[0];
  float* out = (float*)d_out;
  u64* dslots = (u64*)d_ws;                         // 4 KB
  u64* lslots = (u64*)((char*)d_ws + 4096);         // 4 KB
  u32* cnts   = (u32*)((char*)d_ws + 8192);         // 32 B role counters
  const int M = out_size / (NBATCH * 3);            // 2048

  // Zero slots + counters (stale tags must not alias t in 1..M-1).
  hipMemsetAsync(d_ws, 0, 8192 + 256, stream);

  hipLaunchKernelGGL(fps_kernel, dim3(NBATCH * SUBBLOCKS), dim3(NTHREADS), 0,
                     stream, points, out, dslots, lslots, cnts, M);
}